// Round 7
// baseline (170.631 us; speedup 1.0000x reference)
//
#include <hip/hip_runtime.h>

#define B 8
#define N 25200
#define ROW 85
#define NC 80
#define K 2048
#define MAXDET 300
#define NBUCKET 16384
#define CAND_CAP 4096
#define NCHUNK 32   /* K/64 */
#define STILE 64    /* score tile rows */
#define CTR_STRIDE 64   /* u32 stride per batch counter: 256B, no false sharing */

// ---------------------------------------------------------------------------
// Kernel 1: score/cls per box + xyxy boxes4 (bit-identical box math).
// Block (0,b) also zeroes the ready/done counters for kernel 2.
// ---------------------------------------------------------------------------
__global__ void __launch_bounds__(256)
nms_score_kernel(const float* __restrict__ x,
                 float* __restrict__ scores,
                 int* __restrict__ cls_id,
                 float4* __restrict__ boxes4,
                 unsigned* __restrict__ ready,
                 unsigned* __restrict__ done_ctr) {
    int b = blockIdx.y;
    int i0 = blockIdx.x * STILE;
    if (blockIdx.x == 0 && threadIdx.x == 0) {
        ready[b * CTR_STRIDE] = 0u;
        done_ctr[b * CTR_STRIDE] = 0u;
    }
    int rows = N - i0; if (rows > STILE) rows = STILE;
    __shared__ float lx[STILE * ROW];   // 21760 B
    {
        const float4* s4 = (const float4*)(x + ((size_t)b * N + i0) * ROW);
        float4* d4 = (float4*)lx;
        int nv = rows * ROW / 4;        // 1360 or 1020 (both exact)
        for (int k = threadIdx.x; k < nv; k += 256) d4[k] = s4[k];
    }
    __syncthreads();
    int g = threadIdx.x >> 2;          // box in tile
    int q = threadIdx.x & 3;
    if (g >= rows) return;             // uniform across the 4-lane group
    const float* p = lx + g * ROW;
    float obj = p[4];
    float best = -1e30f;
    int bc = 127;
    if (obj > 0.3f) {
        #pragma unroll
        for (int k = 0; k < 20; ++k) {
            int c = q + 4 * k;
            float v = __fmul_rn(p[5 + c], obj);   // exact, no FMA
            if (v > best) { best = v; bc = c; }   // strict >: in-lane first-max
        }
    }
    #pragma unroll
    for (int m = 1; m < 4; m <<= 1) {   // combine: higher v, tie -> smaller class
        float ov = __shfl_xor(best, m, 64);
        int   oc = __shfl_xor(bc, m, 64);
        if (ov > best || (ov == best && oc < bc)) { best = ov; bc = oc; }
    }
    if (q == 0) {
        int i = i0 + g;
        float score = (obj > 0.3f && best > 0.3f) ? best : -1.0f;
        scores[b * N + i] = score;
        cls_id[b * N + i] = (bc == 127) ? 0 : bc;
        float cx = p[0], cy = p[1], w = p[2], h = p[3];
        float hx = __fmul_rn(w, 0.5f);
        float hy = __fmul_rn(h, 0.5f);
        boxes4[b * N + i] = make_float4(__fsub_rn(cx, hx), __fsub_rn(cy, hy),
                                        __fadd_rn(cx, hx), __fadd_rn(cy, hy));
    }
}

// ---------------------------------------------------------------------------
// Kernel 2 (tail): 48 blocks x 1024 threads, two roles.
//   blocks 0..7  : SELECT for batch b. LDS histogram -> scan -> counting sort
//                  -> per-bucket key sort -> gather top-K (staging shifted/area
//                  into the LDS region freed by loff/lcnt16) -> per-class
//                  PACKED rank-sorted member arrays (ppack/pcount) -> release.
//   blocks 8..47 : CLASS-NMS, 16 waves each. Spin on ready[b]; fast path reads
//                  ONE coalesced packed burst per class (no chained mask walk,
//                  no scattered gathers); greedy NMS (exact fp sequence);
//                  keepbits atomicOr; last-finisher wave emits dets/flags.
// ---------------------------------------------------------------------------
__global__ void __launch_bounds__(1024)
nms_tail_kernel(const float* __restrict__ scores,
                const float4* __restrict__ boxes4,
                const int* __restrict__ cls_id,
                float* __restrict__ top_s,
                float* __restrict__ boxes,
                int* __restrict__ clsk,
                float* __restrict__ shifted,
                float* __restrict__ area,
                unsigned long long* __restrict__ keepbits,
                unsigned long long* __restrict__ gclsmask,
                float* __restrict__ ppack,
                unsigned* __restrict__ pcount,
                unsigned* __restrict__ ready,
                unsigned* __restrict__ done_ctr,
                float* __restrict__ out) {
    __shared__ union {
        struct { unsigned loff[NBUCKET]; unsigned lcnt16[NBUCKET / 2]; } a; // 96 KB
        struct { float sx1[K], sy1[K], sx2[K], sy2[K], sar[K]; } b2;        // 40 KB
    } U;
    __shared__ unsigned long long lk[CAND_CAP];      // 32 KB sort keys
    __shared__ unsigned long long lcm[NC * NCHUNK];  // 20 KB class masks
    __shared__ unsigned wsum[16];

    int bid = blockIdx.x;
    int t = threadIdx.x;
    int ln = t & 63, wv = t >> 6;
    unsigned long long below = (ln == 0) ? 0ULL : (~0ULL >> (64 - ln));

    if (bid < B) {
        // ================= SELECT role =================
        int b = bid;
        constexpr int NITER = (N + 1023) / 1024;    // 25

        if (t < NCHUNK) keepbits[b * NCHUNK + t] = 0ULL;
        {   // zero histogram+cursors (one 96KB region), keys, class masks
            uint4 z = {0u, 0u, 0u, 0u};
            uint4* d1 = (uint4*)&U.a;
            for (int k = t; k < (NBUCKET + NBUCKET / 2) / 4; k += 1024) d1[k] = z;
        }
        for (int k = t; k < CAND_CAP; k += 1024) lk[k] = 0ULL;
        for (int k = t; k < NC * NCHUNK; k += 1024) lcm[k] = 0ULL;
        __syncthreads();

        // histogram pass (no register caching: keep VGPR pressure low)
        for (int r = 0; r < NITER; ++r) {
            int i = t + r * 1024;
            if (i < N) {
                float s = scores[b * N + i];
                if (s > 0.0f) {
                    int q = (int)(__fmul_rn(s, 16384.0f));
                    if (q > NBUCKET - 1) q = NBUCKET - 1;
                    atomicAdd(&U.a.loff[q], 1u);
                }
            }
        }
        __syncthreads();

        // descending exclusive scan in place: loff[q] = count in buckets > q
        unsigned v[16];
        unsigned A4 = (unsigned)(NBUCKET - 16 - t * 16) / 4;   // ascending uint4 base
        {
            uint4 u0 = ((uint4*)U.a.loff)[A4 + 0];
            uint4 u1 = ((uint4*)U.a.loff)[A4 + 1];
            uint4 u2 = ((uint4*)U.a.loff)[A4 + 2];
            uint4 u3 = ((uint4*)U.a.loff)[A4 + 3];
            unsigned u[16] = {u0.x,u0.y,u0.z,u0.w, u1.x,u1.y,u1.z,u1.w,
                              u2.x,u2.y,u2.z,u2.w, u3.x,u3.y,u3.z,u3.w};
            #pragma unroll
            for (int k = 0; k < 16; ++k) v[k] = u[15 - k];
        }
        unsigned S = 0;
        #pragma unroll
        for (int k = 0; k < 16; ++k) S += v[k];
        unsigned pref = S;
        #pragma unroll
        for (int o = 1; o < 64; o <<= 1) { unsigned u = __shfl_up(pref, o, 64); if (ln >= o) pref += u; }
        if (ln == 63) wsum[wv] = pref;
        __syncthreads();
        unsigned wbase = 0;
        for (int w = 0; w < wv; ++w) wbase += wsum[w];
        unsigned running = wbase + pref - S;
        {
            unsigned o[16];
            #pragma unroll
            for (int k = 0; k < 16; ++k) { o[15 - k] = running; running += v[k]; }
            ((uint4*)U.a.loff)[A4 + 0] = make_uint4(o[0],  o[1],  o[2],  o[3]);
            ((uint4*)U.a.loff)[A4 + 1] = make_uint4(o[4],  o[5],  o[6],  o[7]);
            ((uint4*)U.a.loff)[A4 + 2] = make_uint4(o[8],  o[9],  o[10], o[11]);
            ((uint4*)U.a.loff)[A4 + 3] = make_uint4(o[12], o[13], o[14], o[15]);
        }
        __syncthreads();

        // placement (counting sort): re-read scores (L2-warm after hist pass)
        for (int r = 0; r < NITER; ++r) {
            int i = t + r * 1024;
            if (i < N) {
                float s = scores[b * N + i];
                if (s > 0.0f) {
                    int q = (int)(__fmul_rn(s, 16384.0f));
                    if (q > NBUCKET - 1) q = NBUCKET - 1;
                    unsigned start = U.a.loff[q];
                    if (start < CAND_CAP) {
                        unsigned sh = (q & 1) * 16;
                        unsigned old = atomicAdd(&U.a.lcnt16[q >> 1], 1u << sh);
                        unsigned rank = (old >> sh) & 0xFFFFu;
                        unsigned pos = start + rank;
                        if (pos < CAND_CAP) {
                            unsigned long long key =
                                ((unsigned long long)__float_as_uint(s) << 32) | (unsigned)(~i);
                            lk[pos] = key;
                        }
                    }
                }
            }
        }
        __syncthreads();

        // per-bucket insertion sort (descending keys), disjoint ranges
        for (int q = t; q < NBUCKET; q += 1024) {
            unsigned start = U.a.loff[q];
            if (start < CAND_CAP) {
                unsigned c = (U.a.lcnt16[q >> 1] >> ((q & 1) * 16)) & 0xFFFFu;
                unsigned m = c;
                if (m > CAND_CAP - start) m = CAND_CAP - start;
                if (m >= 2) {
                    for (unsigned a = start + 1; a < start + m; ++a) {
                        unsigned long long kv = lk[a];
                        unsigned p2 = a;
                        while (p2 > start && lk[p2 - 1] < kv) { lk[p2] = lk[p2 - 1]; --p2; }
                        lk[p2] = kv;
                    }
                }
            }
        }
        __syncthreads();    // loff/lcnt16 dead from here; U.b2 becomes valid

        // gather top-K: globals + LDS staging (U.b2) + class masks
        for (int r = t; r < K; r += 1024) {
            unsigned long long key = lk[r];
            float s;
            int idx;
            float x1, y1, x2, y2;
            int c;
            if (key == 0ULL) {
                s = -1.0f; x1 = y1 = x2 = y2 = 0.0f; c = 0;
            } else {
                s = __uint_as_float((unsigned)(key >> 32));
                idx = (int)(~(unsigned)key);
                float4 bb = boxes4[(size_t)b * N + idx];
                x1 = bb.x; y1 = bb.y; x2 = bb.z; y2 = bb.w;
                c = cls_id[b * N + idx];
                atomicOr(&lcm[c * NCHUNK + (r >> 6)], 1ULL << (r & 63));
            }
            int o = b * K + r;
            top_s[o] = s;
            boxes[o * 4 + 0] = x1; boxes[o * 4 + 1] = y1;
            boxes[o * 4 + 2] = x2; boxes[o * 4 + 3] = y2;
            clsk[o] = c;
            float sh = __fmul_rn((float)c, 4096.0f);
            float sx1 = __fadd_rn(x1, sh), sy1 = __fadd_rn(y1, sh);
            float sx2 = __fadd_rn(x2, sh), sy2 = __fadd_rn(y2, sh);
            shifted[o * 4 + 0] = sx1; shifted[o * 4 + 1] = sy1;
            shifted[o * 4 + 2] = sx2; shifted[o * 4 + 3] = sy2;
            float ar = __fmul_rn(__fsub_rn(sx2, sx1), __fsub_rn(sy2, sy1));
            area[o] = ar;
            U.b2.sx1[r] = sx1; U.b2.sy1[r] = sy1;
            U.b2.sx2[r] = sx2; U.b2.sy2[r] = sy2;
            U.b2.sar[r] = ar;
        }
        __syncthreads();

        // per-class packed, rank-sorted member arrays (wave wv: classes wv,wv+16,..)
        for (int c = wv; c < NC; c += 16) {
            int n = 0;
            for (int ch = 0; ch < NCHUNK; ++ch) {
                unsigned long long m = lcm[c * NCHUNK + ch];   // LDS, wave-uniform
                if ((m >> ln) & 1ULL) {
                    int pos = n + __popcll(m & below);
                    if (pos < 64) {
                        int r = ch * 64 + ln;
                        float* pe = ppack + (((size_t)b * NC + c) * 64 + pos) * 6;
                        pe[0] = U.b2.sx1[r]; pe[1] = U.b2.sy1[r];
                        pe[2] = U.b2.sx2[r]; pe[3] = U.b2.sy2[r];
                        pe[4] = U.b2.sar[r];
                        pe[5] = __uint_as_float((unsigned)r);
                    }
                }
                n += __popcll(m);
            }
            if (ln == 0) pcount[b * NC + c] = (unsigned)n;
        }
        // export class masks (general-path fallback)
        for (int k = t; k < NC * NCHUNK; k += 1024)
            gclsmask[(size_t)b * NC * NCHUNK + k] = lcm[k];
        __syncthreads();
        // release: device-scope fence (L2 writeback) then flag
        if (t == 0) {
            __threadfence();
            atomicExch(&ready[b * CTR_STRIDE], 1u);
        }
        return;
    }

    // ================= CLASS-NMS role =================
    int gid = bid - B;          // 0..39
    int b = gid / 5;
    int grp = gid % 5;
    int c = grp * 16 + wv;      // this wave's class, 0..79

    // acquire: spin on ready[b], invalidate caches, block-wide barrier
    if (t == 0) {
        while (atomicOr(&ready[b * CTR_STRIDE], 0u) == 0u)
            __builtin_amdgcn_s_sleep(8);
        __threadfence();
    }
    __syncthreads();

    int n = (int)pcount[b * NC + c];

    if (n > 0 && n <= 64) {
        // fast path: ONE coalesced packed burst; member ln in lane ln
        float x1 = 0.f, y1 = 0.f, x2 = 0.f, y2 = 0.f, ar = 0.f;
        int r = -1;
        if (ln < n) {
            const float* pe = ppack + (((size_t)b * NC + c) * 64 + ln) * 6;
            x1 = pe[0]; y1 = pe[1]; x2 = pe[2]; y2 = pe[3]; ar = pe[4];
            r = (int)__float_as_uint(pe[5]);
        }
        unsigned long long keepw = (n == 64) ? ~0ULL : ((1ULL << n) - 1ULL);
        for (int i = 0; i < n; ++i) {
            if (!((keepw >> i) & 1ULL)) continue;   // uniform
            float bx1 = __shfl(x1, i, 64), by1 = __shfl(y1, i, 64);
            float bx2 = __shfl(x2, i, 64), by2 = __shfl(y2, i, 64);
            float ba  = __shfl(ar, i, 64);
            bool cond = false;
            if (ln > i && ln < n) {
                float lx = fmaxf(bx1, x1), ly = fmaxf(by1, y1);
                float rx = fminf(bx2, x2), ry = fminf(by2, y2);
                float w = fmaxf(__fsub_rn(rx, lx), 0.0f);
                float h = fmaxf(__fsub_rn(ry, ly), 0.0f);
                float inter = __fmul_rn(w, h);
                float denom = __fadd_rn(__fsub_rn(__fadd_rn(ba, ar), inter), 1e-9f);
                cond = __fdiv_rn(inter, denom) > 0.6f;   // exact ref order
            }
            keepw &= ~__ballot(cond);
        }
        if (ln < n && ((keepw >> ln) & 1ULL))
            atomicOr(&keepbits[b * NCHUNK + (r >> 6)], 1ULL << (r & 63));
    } else if (n > 64) {
        // general path (n > 64): wave-local, register-distributed keep bits.
        // Correctness-only; unreachable for this data distribution.
        const unsigned long long* cm = gclsmask + ((size_t)b * NC + c) * NCHUNK;
        unsigned long long membw = (ln < NCHUNK) ? cm[ln] : 0ULL;
        unsigned long long keepw2 = membw;
        for (int i = 0; i < K; ++i) {
            int ch = i >> 6;
            unsigned long long mw = __shfl(membw, ch, 64);
            unsigned long long kw = __shfl(keepw2, ch, 64);
            unsigned long long bi = 1ULL << (i & 63);
            if (!(mw & kw & bi)) continue;   // uniform (shfl results uniform)
            const float* sbi = shifted + ((size_t)b * K + i) * 4;
            float bx1 = sbi[0], by1 = sbi[1], bx2 = sbi[2], by2 = sbi[3];
            float ba = area[b * K + i];
            for (int c2 = ch; c2 < NCHUNK; ++c2) {
                int j = c2 * 64 + ln;
                unsigned long long mw2 = __shfl(membw, c2, 64);
                bool cond = false;
                if (j > i && ((mw2 >> ln) & 1ULL)) {
                    const float* sbj = shifted + ((size_t)b * K + j) * 4;
                    float x1 = sbj[0], y1 = sbj[1], x2 = sbj[2], y2 = sbj[3];
                    float arj = area[b * K + j];
                    float lx = fmaxf(bx1, x1), ly = fmaxf(by1, y1);
                    float rx = fminf(bx2, x2), ry = fminf(by2, y2);
                    float w = fmaxf(__fsub_rn(rx, lx), 0.0f);
                    float h = fmaxf(__fsub_rn(ry, ly), 0.0f);
                    float inter = __fmul_rn(w, h);
                    float denom = __fadd_rn(__fsub_rn(__fadd_rn(ba, arj), inter), 1e-9f);
                    cond = __fdiv_rn(inter, denom) > 0.6f;
                }
                unsigned long long sup = __ballot(cond);
                if (ln == c2) keepw2 &= ~sup;
            }
        }
        if (ln < NCHUNK && (keepw2 & membw))
            atomicOr(&keepbits[b * NCHUNK + ln], keepw2 & membw);
    }

    // ---- last-finisher output phase (one wave per batch) ----
    __threadfence();
    unsigned old = 0;
    if (ln == 0) old = atomicAdd(&done_ctr[b * CTR_STRIDE], 1u);
    old = (unsigned)__shfl((int)old, 0, 64);
    if (old == NC - 1) {
        __threadfence();
        // kept bits: lane ch holds chunk ch (register-distributed, no LDS)
        unsigned long long kw = 0ULL;
        if (ln < NCHUNK) kw = atomicOr(&keepbits[b * NCHUNK + ln], 0ULL);
        int total = 0;
        for (int ch = 0; ch < NCHUNK; ++ch) total += __popcll(__shfl(kw, ch, 64));

        float* dets  = out + (size_t)b * MAXDET * 6;
        float* flags = out + (size_t)B * MAXDET * 6 + (size_t)b * MAXDET;
        int kc = 0, nc2 = 0;
        for (int ch = 0; ch < NCHUNK; ++ch) {
            int i = ch * 64 + ln;
            unsigned long long m = __shfl(kw, ch, 64);
            bool k = ((m >> ln) & 1ULL) != 0ULL;
            int pc = __popcll(m);
            int slot = k ? (kc + __popcll(m & below))
                         : (total + nc2 + __popcll((~m) & below));
            if (slot < MAXDET) {
                int o = b * K + i;
                dets[slot * 6 + 0] = boxes[o * 4 + 0];
                dets[slot * 6 + 1] = boxes[o * 4 + 1];
                dets[slot * 6 + 2] = boxes[o * 4 + 2];
                dets[slot * 6 + 3] = boxes[o * 4 + 3];
                dets[slot * 6 + 4] = top_s[o];
                dets[slot * 6 + 5] = (float)clsk[o];
                flags[slot] = k ? 1.0f : 0.0f;
            }
            kc += pc;
            nc2 += 64 - pc;
        }
    }
}

// ---------------------------------------------------------------------------
extern "C" void kernel_launch(void* const* d_in, const int* in_sizes, int n_in,
                              void* d_out, int out_size, void* d_ws, size_t ws_size,
                              hipStream_t stream) {
    const float* x = (const float*)d_in[0];
    float* out = (float*)d_out;

    char* ws = (char*)d_ws;
    size_t off = 0;
    auto alloc = [&](size_t bytes) -> void* {
        void* p = ws + off;
        off += bytes;
        off = (off + 255) & ~(size_t)255;
        return p;
    };

    float*    scores = (float*)    alloc((size_t)B * N * 4);
    int*      cls_id = (int*)      alloc((size_t)B * N * 4);
    float4*   boxes4 = (float4*)   alloc((size_t)B * N * 16);
    float*    top_s  = (float*)    alloc((size_t)B * K * 4);
    float*    boxes  = (float*)    alloc((size_t)B * K * 4 * 4);
    int*      clsk   = (int*)      alloc((size_t)B * K * 4);
    float*    shifted= (float*)    alloc((size_t)B * K * 4 * 4);
    float*    area   = (float*)    alloc((size_t)B * K * 4);
    unsigned long long* keepbits = (unsigned long long*) alloc((size_t)B * NCHUNK * 8);
    unsigned long long* gclsmask = (unsigned long long*) alloc((size_t)B * NC * NCHUNK * 8);
    float*    ppack  = (float*)    alloc((size_t)B * NC * 64 * 6 * 4);
    unsigned* pcount = (unsigned*) alloc((size_t)B * NC * 4);
    unsigned* ready    = (unsigned*) alloc((size_t)B * CTR_STRIDE * 4);
    unsigned* done_ctr = (unsigned*) alloc((size_t)B * CTR_STRIDE * 4);
    (void)ws_size; // needs ~7.2 MB

    nms_score_kernel<<<dim3((N + STILE - 1) / STILE, B), 256, 0, stream>>>(
        x, scores, cls_id, boxes4, ready, done_ctr);
    nms_tail_kernel<<<B + 5 * B, 1024, 0, stream>>>(
        scores, boxes4, cls_id, top_s, boxes, clsk, shifted, area,
        keepbits, gclsmask, ppack, pcount, ready, done_ctr, out);
}

// Round 8
// 141.275 us; speedup vs baseline: 1.2078x; 1.2078x over previous
//
#include <hip/hip_runtime.h>

#define B 8
#define N 25200
#define ROW 85
#define NC 80
#define K 2048
#define MAXDET 300
#define NBUCKET 16384
#define CAND_CAP 4096
#define NCHUNK 32   /* K/64 */
#define STILE 64    /* score tile rows */
#define CTR_STRIDE 64   /* u32 stride per batch counter: 256B, no false sharing */

// ---------------------------------------------------------------------------
// Kernel 1: score/cls per box + xyxy boxes4 (bit-identical box math).
// Block (0,b) also zeroes the ready/done counters for kernel 2.
// ---------------------------------------------------------------------------
__global__ void __launch_bounds__(256)
nms_score_kernel(const float* __restrict__ x,
                 float* __restrict__ scores,
                 int* __restrict__ cls_id,
                 float4* __restrict__ boxes4,
                 unsigned* __restrict__ ready,
                 unsigned* __restrict__ done_ctr) {
    int b = blockIdx.y;
    int i0 = blockIdx.x * STILE;
    if (blockIdx.x == 0 && threadIdx.x == 0) {
        ready[b * CTR_STRIDE] = 0u;
        done_ctr[b * CTR_STRIDE] = 0u;
    }
    int rows = N - i0; if (rows > STILE) rows = STILE;
    __shared__ float lx[STILE * ROW];   // 21760 B
    {
        const float4* s4 = (const float4*)(x + ((size_t)b * N + i0) * ROW);
        float4* d4 = (float4*)lx;
        int nv = rows * ROW / 4;        // 1360 or 1020 (both exact)
        for (int k = threadIdx.x; k < nv; k += 256) d4[k] = s4[k];
    }
    __syncthreads();
    int g = threadIdx.x >> 2;          // box in tile
    int q = threadIdx.x & 3;
    if (g >= rows) return;             // uniform across the 4-lane group
    const float* p = lx + g * ROW;
    float obj = p[4];
    float best = -1e30f;
    int bc = 127;
    if (obj > 0.3f) {
        #pragma unroll
        for (int k = 0; k < 20; ++k) {
            int c = q + 4 * k;
            float v = __fmul_rn(p[5 + c], obj);   // exact, no FMA
            if (v > best) { best = v; bc = c; }   // strict >: in-lane first-max
        }
    }
    #pragma unroll
    for (int m = 1; m < 4; m <<= 1) {   // combine: higher v, tie -> smaller class
        float ov = __shfl_xor(best, m, 64);
        int   oc = __shfl_xor(bc, m, 64);
        if (ov > best || (ov == best && oc < bc)) { best = ov; bc = oc; }
    }
    if (q == 0) {
        int i = i0 + g;
        float score = (obj > 0.3f && best > 0.3f) ? best : -1.0f;
        scores[b * N + i] = score;
        cls_id[b * N + i] = (bc == 127) ? 0 : bc;
        float cx = p[0], cy = p[1], w = p[2], h = p[3];
        float hx = __fmul_rn(w, 0.5f);
        float hy = __fmul_rn(h, 0.5f);
        boxes4[b * N + i] = make_float4(__fsub_rn(cx, hx), __fsub_rn(cy, hy),
                                        __fadd_rn(cx, hx), __fadd_rn(cy, hy));
    }
}

// ---------------------------------------------------------------------------
// Kernel 2 (tail): 48 blocks x 1024 threads, two roles.
//   blocks 0..7  : SELECT for batch b — MINIMAL serial core: LDS histogram ->
//                  scan -> counting-sort placement -> per-bucket key sort ->
//                  export 2048 sorted keys (coalesced 16 KB) -> release.
//                  NO gather, NO per-rank stores, NO mask building.
//   blocks 8..47 : CLASS-NMS, 16 waves each (5 blocks/batch). Spin on
//                  ready[b]; load keys -> LDS; parallel cls_id gather; LDS
//                  class masks; per-wave greedy NMS with member data computed
//                  in-lane from boxes4 (exact fp sequence select used);
//                  keepbits atomicOr; last-finisher wave derives dets/flags
//                  directly from keys + boxes4 + cls_id.
// ---------------------------------------------------------------------------
__global__ void __launch_bounds__(1024, 1)
nms_tail_kernel(const float* __restrict__ scores,
                const float4* __restrict__ boxes4,
                const int* __restrict__ cls_id,
                unsigned long long* __restrict__ gkeys,
                unsigned long long* __restrict__ keepbits,
                unsigned* __restrict__ ready,
                unsigned* __restrict__ done_ctr,
                float* __restrict__ out) {
    __shared__ union {
        struct {   // SELECT role: 128 KB
            unsigned loff[NBUCKET];              // 64 KB hist -> start ranks
            unsigned lcnt16[NBUCKET / 2];        // 32 KB packed u16 cursors
            unsigned long long lk[CAND_CAP];     // 32 KB sort keys
        } s;
        struct {   // CONSUMER role: 36 KB
            unsigned long long keys[K];          // 16 KB sorted keys
            unsigned long long lcm[NC * NCHUNK]; // 20 KB class masks
        } c;
    } U;
    __shared__ unsigned wsum[16];

    int bid = blockIdx.x;
    int t = threadIdx.x;
    int ln = t & 63, wv = t >> 6;
    unsigned long long below = (ln == 0) ? 0ULL : (~0ULL >> (64 - ln));

    if (bid < B) {
        // ================= SELECT role =================
        int b = bid;
        constexpr int NITER = (N + 1023) / 1024;    // 25

        if (t < NCHUNK) keepbits[b * NCHUNK + t] = 0ULL;
        {   // zero histogram + cursors
            uint4 z = {0u, 0u, 0u, 0u};
            uint4* d1 = (uint4*)U.s.loff;
            for (int k = t; k < (NBUCKET + NBUCKET / 2) / 4; k += 1024) d1[k] = z;
        }
        for (int k = t; k < CAND_CAP; k += 1024) U.s.lk[k] = 0ULL;
        __syncthreads();

        // histogram pass: single global read, cache scores in registers
        float sreg[NITER];
        #pragma unroll
        for (int r = 0; r < NITER; ++r) {
            int i = t + r * 1024;
            float s = (i < N) ? scores[b * N + i] : -1.0f;
            sreg[r] = s;
            if (s > 0.0f) {
                int q = (int)(__fmul_rn(s, 16384.0f));
                if (q > NBUCKET - 1) q = NBUCKET - 1;
                atomicAdd(&U.s.loff[q], 1u);
            }
        }
        __syncthreads();

        // descending exclusive scan in place: loff[q] = count in buckets > q
        unsigned v[16];
        unsigned A4 = (unsigned)(NBUCKET - 16 - t * 16) / 4;   // ascending uint4 base
        {
            uint4 u0 = ((uint4*)U.s.loff)[A4 + 0];
            uint4 u1 = ((uint4*)U.s.loff)[A4 + 1];
            uint4 u2 = ((uint4*)U.s.loff)[A4 + 2];
            uint4 u3 = ((uint4*)U.s.loff)[A4 + 3];
            unsigned u[16] = {u0.x,u0.y,u0.z,u0.w, u1.x,u1.y,u1.z,u1.w,
                              u2.x,u2.y,u2.z,u2.w, u3.x,u3.y,u3.z,u3.w};
            #pragma unroll
            for (int k = 0; k < 16; ++k) v[k] = u[15 - k];
        }
        unsigned S = 0;
        #pragma unroll
        for (int k = 0; k < 16; ++k) S += v[k];
        unsigned pref = S;
        #pragma unroll
        for (int o = 1; o < 64; o <<= 1) { unsigned u = __shfl_up(pref, o, 64); if (ln >= o) pref += u; }
        if (ln == 63) wsum[wv] = pref;
        __syncthreads();
        unsigned wbase = 0;
        for (int w = 0; w < wv; ++w) wbase += wsum[w];
        unsigned running = wbase + pref - S;
        {
            unsigned o[16];
            #pragma unroll
            for (int k = 0; k < 16; ++k) { o[15 - k] = running; running += v[k]; }
            ((uint4*)U.s.loff)[A4 + 0] = make_uint4(o[0],  o[1],  o[2],  o[3]);
            ((uint4*)U.s.loff)[A4 + 1] = make_uint4(o[4],  o[5],  o[6],  o[7]);
            ((uint4*)U.s.loff)[A4 + 2] = make_uint4(o[8],  o[9],  o[10], o[11]);
            ((uint4*)U.s.loff)[A4 + 3] = make_uint4(o[12], o[13], o[14], o[15]);
        }
        __syncthreads();

        // placement (counting sort) from register-cached scores
        #pragma unroll
        for (int r = 0; r < NITER; ++r) {
            float s = sreg[r];
            if (s > 0.0f) {
                int i = t + r * 1024;
                int q = (int)(__fmul_rn(s, 16384.0f));
                if (q > NBUCKET - 1) q = NBUCKET - 1;
                unsigned start = U.s.loff[q];
                if (start < CAND_CAP) {
                    unsigned sh = (q & 1) * 16;
                    unsigned old = atomicAdd(&U.s.lcnt16[q >> 1], 1u << sh);
                    unsigned rank = (old >> sh) & 0xFFFFu;
                    unsigned pos = start + rank;
                    if (pos < CAND_CAP) {
                        unsigned long long key =
                            ((unsigned long long)__float_as_uint(s) << 32) | (unsigned)(~i);
                        U.s.lk[pos] = key;
                    }
                }
            }
        }
        __syncthreads();

        // per-bucket insertion sort (descending keys), disjoint ranges
        for (int q = t; q < NBUCKET; q += 1024) {
            unsigned start = U.s.loff[q];
            if (start < CAND_CAP) {
                unsigned c = (U.s.lcnt16[q >> 1] >> ((q & 1) * 16)) & 0xFFFFu;
                unsigned m = c;
                if (m > CAND_CAP - start) m = CAND_CAP - start;
                if (m >= 2) {
                    for (unsigned a = start + 1; a < start + m; ++a) {
                        unsigned long long kv = U.s.lk[a];
                        unsigned p2 = a;
                        while (p2 > start && U.s.lk[p2 - 1] < kv) { U.s.lk[p2] = U.s.lk[p2 - 1]; --p2; }
                        U.s.lk[p2] = kv;
                    }
                }
            }
        }
        __syncthreads();

        // export the top-K sorted keys (coalesced, 16 KB) and release
        for (int r = t; r < K; r += 1024)
            gkeys[(size_t)b * K + r] = U.s.lk[r];
        __syncthreads();
        if (t == 0) {
            __threadfence();
            atomicExch(&ready[b * CTR_STRIDE], 1u);
        }
        return;
    }

    // ================= CLASS-NMS role =================
    int gid = bid - B;          // 0..39
    int b = gid / 5;
    int grp = gid % 5;
    int c = grp * 16 + wv;      // this wave's class, 0..79

    // acquire: spin on ready[b], invalidate caches, block-wide barrier
    if (t == 0) {
        while (atomicOr(&ready[b * CTR_STRIDE], 0u) == 0u)
            __builtin_amdgcn_s_sleep(8);
        __threadfence();
    }
    __syncthreads();

    // load sorted keys -> LDS; zero class masks
    for (int r = t; r < K; r += 1024) U.c.keys[r] = gkeys[(size_t)b * K + r];
    for (int k = t; k < NC * NCHUNK; k += 1024) U.c.lcm[k] = 0ULL;
    __syncthreads();

    // parallel class-mask build (1024 threads x 2 ranks)
    for (int r = t; r < K; r += 1024) {
        unsigned long long key = U.c.keys[r];
        if (key != 0ULL) {
            int idx = (int)(~(unsigned)key);
            int cc = cls_id[b * N + idx];
            atomicOr(&U.c.lcm[cc * NCHUNK + (r >> 6)], 1ULL << (r & 63));
        }
    }
    __syncthreads();

    // register compaction from LDS masks: lane ln -> ln-th member of class c
    int n = 0, r = -1, ch_i = -1, myk = -1;
    unsigned long long mych = 0ULL;
    for (int ch = 0; ch < NCHUNK; ++ch) {
        unsigned long long m = U.c.lcm[c * NCHUNK + ch];   // LDS, wave-uniform
        int cnt = __popcll(m);
        if (myk < 0 && ln < n + cnt) { mych = m; myk = ln - n; ch_i = ch; }
        n += cnt;
    }
    if (myk >= 0) {
        unsigned long long mm = mych;
        for (int z = 0; z < myk; ++z) mm &= mm - 1;
        r = ch_i * 64 + (int)__builtin_ctzll(mm);
    }

    float shf = __fmul_rn((float)c, 4096.0f);   // class shift (uniform)

    if (n > 0 && n <= 64) {
        // fast path: member ln computes its shifted box in-lane from boxes4
        float x1 = 0.f, y1 = 0.f, x2 = 0.f, y2 = 0.f, ar = 0.f;
        if (ln < n) {
            unsigned long long key = U.c.keys[r];
            int idx = (int)(~(unsigned)key);
            float4 bb = boxes4[(size_t)b * N + idx];
            x1 = __fadd_rn(bb.x, shf); y1 = __fadd_rn(bb.y, shf);
            x2 = __fadd_rn(bb.z, shf); y2 = __fadd_rn(bb.w, shf);
            ar = __fmul_rn(__fsub_rn(x2, x1), __fsub_rn(y2, y1));
        }
        unsigned long long keepw = (n == 64) ? ~0ULL : ((1ULL << n) - 1ULL);
        for (int i = 0; i < n; ++i) {
            if (!((keepw >> i) & 1ULL)) continue;   // uniform
            float bx1 = __shfl(x1, i, 64), by1 = __shfl(y1, i, 64);
            float bx2 = __shfl(x2, i, 64), by2 = __shfl(y2, i, 64);
            float ba  = __shfl(ar, i, 64);
            bool cond = false;
            if (ln > i && ln < n) {
                float lx = fmaxf(bx1, x1), ly = fmaxf(by1, y1);
                float rx = fminf(bx2, x2), ry = fminf(by2, y2);
                float w = fmaxf(__fsub_rn(rx, lx), 0.0f);
                float h = fmaxf(__fsub_rn(ry, ly), 0.0f);
                float inter = __fmul_rn(w, h);
                float denom = __fadd_rn(__fsub_rn(__fadd_rn(ba, ar), inter), 1e-9f);
                cond = __fdiv_rn(inter, denom) > 0.6f;   // exact ref order
            }
            keepw &= ~__ballot(cond);
        }
        if (ln < n && ((keepw >> ln) & 1ULL))
            atomicOr(&keepbits[b * NCHUNK + (r >> 6)], 1ULL << (r & 63));
    } else if (n > 64) {
        // general path (n > 64): wave-local register-distributed keep bits.
        // Correctness-only; unreachable for this data distribution.
        unsigned long long membw = (ln < NCHUNK) ? U.c.lcm[c * NCHUNK + ln] : 0ULL;
        unsigned long long keepw2 = membw;
        for (int i = 0; i < K; ++i) {
            int ch = i >> 6;
            unsigned long long mw = __shfl(membw, ch, 64);
            unsigned long long kw = __shfl(keepw2, ch, 64);
            unsigned long long bi = 1ULL << (i & 63);
            if (!(mw & kw & bi)) continue;   // uniform (shfl results uniform)
            unsigned long long keyi = U.c.keys[i];             // uniform
            int idxi = (int)(~(unsigned)keyi);
            float4 bi4 = boxes4[(size_t)b * N + idxi];
            float bx1 = __fadd_rn(bi4.x, shf), by1 = __fadd_rn(bi4.y, shf);
            float bx2 = __fadd_rn(bi4.z, shf), by2 = __fadd_rn(bi4.w, shf);
            float ba = __fmul_rn(__fsub_rn(bx2, bx1), __fsub_rn(by2, by1));
            for (int c2 = ch; c2 < NCHUNK; ++c2) {
                int j = c2 * 64 + ln;
                unsigned long long mw2 = __shfl(membw, c2, 64);
                bool cond = false;
                if (j > i && ((mw2 >> ln) & 1ULL)) {
                    unsigned long long keyj = U.c.keys[j];
                    int idxj = (int)(~(unsigned)keyj);
                    float4 bj4 = boxes4[(size_t)b * N + idxj];
                    float x1 = __fadd_rn(bj4.x, shf), y1 = __fadd_rn(bj4.y, shf);
                    float x2 = __fadd_rn(bj4.z, shf), y2 = __fadd_rn(bj4.w, shf);
                    float arj = __fmul_rn(__fsub_rn(x2, x1), __fsub_rn(y2, y1));
                    float lx = fmaxf(bx1, x1), ly = fmaxf(by1, y1);
                    float rx = fminf(bx2, x2), ry = fminf(by2, y2);
                    float w = fmaxf(__fsub_rn(rx, lx), 0.0f);
                    float h = fmaxf(__fsub_rn(ry, ly), 0.0f);
                    float inter = __fmul_rn(w, h);
                    float denom = __fadd_rn(__fsub_rn(__fadd_rn(ba, arj), inter), 1e-9f);
                    cond = __fdiv_rn(inter, denom) > 0.6f;
                }
                unsigned long long sup = __ballot(cond);
                if (ln == c2) keepw2 &= ~sup;
            }
        }
        if (ln < NCHUNK && (keepw2 & membw))
            atomicOr(&keepbits[b * NCHUNK + ln], keepw2 & membw);
    }

    // ---- last-finisher output phase (one wave per batch) ----
    __threadfence();
    unsigned old = 0;
    if (ln == 0) old = atomicAdd(&done_ctr[b * CTR_STRIDE], 1u);
    old = (unsigned)__shfl((int)old, 0, 64);
    if (old == NC - 1) {
        __threadfence();
        // kept bits: lane ch holds chunk ch (register-distributed)
        unsigned long long kw = 0ULL;
        if (ln < NCHUNK) kw = atomicOr(&keepbits[b * NCHUNK + ln], 0ULL);
        int total = 0;
        for (int ch = 0; ch < NCHUNK; ++ch) total += __popcll(__shfl(kw, ch, 64));

        float* dets  = out + (size_t)b * MAXDET * 6;
        float* flags = out + (size_t)B * MAXDET * 6 + (size_t)b * MAXDET;
        int kc = 0, nc2 = 0;
        for (int ch = 0; ch < NCHUNK; ++ch) {
            int i = ch * 64 + ln;
            unsigned long long m = __shfl(kw, ch, 64);
            bool k = ((m >> ln) & 1ULL) != 0ULL;
            int pc = __popcll(m);
            int slot = k ? (kc + __popcll(m & below))
                         : (total + nc2 + __popcll((~m) & below));
            if (slot < MAXDET) {
                unsigned long long key = U.c.keys[i];
                float s, ox1, oy1, ox2, oy2; int oc;
                if (key == 0ULL) {
                    s = -1.0f; ox1 = oy1 = ox2 = oy2 = 0.0f; oc = 0;
                } else {
                    s = __uint_as_float((unsigned)(key >> 32));
                    int idx = (int)(~(unsigned)key);
                    float4 bb = boxes4[(size_t)b * N + idx];
                    ox1 = bb.x; oy1 = bb.y; ox2 = bb.z; oy2 = bb.w;
                    oc = cls_id[b * N + idx];
                }
                dets[slot * 6 + 0] = ox1;
                dets[slot * 6 + 1] = oy1;
                dets[slot * 6 + 2] = ox2;
                dets[slot * 6 + 3] = oy2;
                dets[slot * 6 + 4] = s;
                dets[slot * 6 + 5] = (float)oc;
                flags[slot] = k ? 1.0f : 0.0f;
            }
            kc += pc;
            nc2 += 64 - pc;
        }
    }
}

// ---------------------------------------------------------------------------
extern "C" void kernel_launch(void* const* d_in, const int* in_sizes, int n_in,
                              void* d_out, int out_size, void* d_ws, size_t ws_size,
                              hipStream_t stream) {
    const float* x = (const float*)d_in[0];
    float* out = (float*)d_out;

    char* ws = (char*)d_ws;
    size_t off = 0;
    auto alloc = [&](size_t bytes) -> void* {
        void* p = ws + off;
        off += bytes;
        off = (off + 255) & ~(size_t)255;
        return p;
    };

    float*    scores = (float*)    alloc((size_t)B * N * 4);
    int*      cls_id = (int*)      alloc((size_t)B * N * 4);
    float4*   boxes4 = (float4*)   alloc((size_t)B * N * 16);
    unsigned long long* gkeys    = (unsigned long long*) alloc((size_t)B * K * 8);
    unsigned long long* keepbits = (unsigned long long*) alloc((size_t)B * NCHUNK * 8);
    unsigned* ready    = (unsigned*) alloc((size_t)B * CTR_STRIDE * 4);
    unsigned* done_ctr = (unsigned*) alloc((size_t)B * CTR_STRIDE * 4);
    (void)ws_size; // needs ~2.7 MB

    nms_score_kernel<<<dim3((N + STILE - 1) / STILE, B), 256, 0, stream>>>(
        x, scores, cls_id, boxes4, ready, done_ctr);
    nms_tail_kernel<<<B + 5 * B, 1024, 0, stream>>>(
        scores, boxes4, cls_id, gkeys, keepbits, ready, done_ctr, out);
}

// Round 9
// 139.568 us; speedup vs baseline: 1.2226x; 1.0122x over previous
//
#include <hip/hip_runtime.h>

#define B 8
#define N 25200
#define ROW 85
#define NC 80
#define K 2048
#define MAXDET 300
#define NBUCKET 4096
#define CAND_CAP 4096
#define NCHUNK 32   /* K/64 */
#define STILE 64    /* score tile rows */
#define CTR_STRIDE 64   /* u32 stride per batch counter: 256B, no false sharing */

// ---------------------------------------------------------------------------
// Kernel 1: score/cls per box + xyxy boxes4 (bit-identical box math).
// Block (0,b) also zeroes ready/done counters and keepbits for kernel 2.
// ---------------------------------------------------------------------------
__global__ void __launch_bounds__(256)
nms_score_kernel(const float* __restrict__ x,
                 float* __restrict__ scores,
                 int* __restrict__ cls_id,
                 float4* __restrict__ boxes4,
                 unsigned* __restrict__ ready,
                 unsigned* __restrict__ done_ctr,
                 unsigned long long* __restrict__ keepbits) {
    int b = blockIdx.y;
    int i0 = blockIdx.x * STILE;
    if (blockIdx.x == 0) {
        if (threadIdx.x == 0) {
            ready[b * CTR_STRIDE] = 0u;
            done_ctr[b * CTR_STRIDE] = 0u;
        }
        if (threadIdx.x < NCHUNK) keepbits[b * NCHUNK + threadIdx.x] = 0ULL;
    }
    int rows = N - i0; if (rows > STILE) rows = STILE;
    __shared__ float lx[STILE * ROW];   // 21760 B
    {
        const float4* s4 = (const float4*)(x + ((size_t)b * N + i0) * ROW);
        float4* d4 = (float4*)lx;
        int nv = rows * ROW / 4;        // 1360 or 1020 (both exact)
        for (int k = threadIdx.x; k < nv; k += 256) d4[k] = s4[k];
    }
    __syncthreads();
    int g = threadIdx.x >> 2;          // box in tile
    int q = threadIdx.x & 3;
    if (g >= rows) return;             // uniform across the 4-lane group
    const float* p = lx + g * ROW;
    float obj = p[4];
    float best = -1e30f;
    int bc = 127;
    if (obj > 0.3f) {
        #pragma unroll
        for (int k = 0; k < 20; ++k) {
            int c = q + 4 * k;
            float v = __fmul_rn(p[5 + c], obj);   // exact, no FMA
            if (v > best) { best = v; bc = c; }   // strict >: in-lane first-max
        }
    }
    #pragma unroll
    for (int m = 1; m < 4; m <<= 1) {   // combine: higher v, tie -> smaller class
        float ov = __shfl_xor(best, m, 64);
        int   oc = __shfl_xor(bc, m, 64);
        if (ov > best || (ov == best && oc < bc)) { best = ov; bc = oc; }
    }
    if (q == 0) {
        int i = i0 + g;
        float score = (obj > 0.3f && best > 0.3f) ? best : -1.0f;
        scores[b * N + i] = score;
        cls_id[b * N + i] = (bc == 127) ? 0 : bc;
        float cx = p[0], cy = p[1], w = p[2], h = p[3];
        float hx = __fmul_rn(w, 0.5f);
        float hy = __fmul_rn(h, 0.5f);
        boxes4[b * N + i] = make_float4(__fsub_rn(cx, hx), __fsub_rn(cy, hy),
                                        __fadd_rn(cx, hx), __fadd_rn(cy, hy));
    }
}

// ---------------------------------------------------------------------------
// Kernel 2 (tail): 48 blocks x 1024 threads, two roles.
//   blocks 0..7  : SELECT for batch b — minimal serial core with 4096 bins
//                  (bin width only redistributes work between counting sort
//                  and the canonicalizing full-key insertion sort; final
//                  descending (score,~idx) order is identical): histogram ->
//                  scan -> placement -> per-bucket key sort -> export 2048
//                  sorted keys -> release.
//   blocks 8..47 : CLASS-NMS, 16 waves each (5 blocks/batch). Spin on
//                  ready[b]; keys -> LDS; parallel cls_id gather; LDS class
//                  masks; per-wave greedy NMS (exact fp sequence); keepbits
//                  atomicOr; last-finisher wave computes per-chunk kept
//                  prefixes, then its WHOLE BLOCK emits dets/flags in
//                  parallel (2 chunks per wave).
// ---------------------------------------------------------------------------
__global__ void __launch_bounds__(1024, 1)
nms_tail_kernel(const float* __restrict__ scores,
                const float4* __restrict__ boxes4,
                const int* __restrict__ cls_id,
                unsigned long long* __restrict__ gkeys,
                unsigned long long* __restrict__ keepbits,
                unsigned* __restrict__ ready,
                unsigned* __restrict__ done_ctr,
                float* __restrict__ out) {
    __shared__ union {
        struct {   // SELECT role: 56 KB
            unsigned loff[NBUCKET];              // 16 KB hist -> start ranks
            unsigned lcnt16[NBUCKET / 2];        // 8 KB packed u16 cursors
            unsigned long long lk[CAND_CAP];     // 32 KB sort keys
        } s;
        struct {   // CONSUMER role: ~37 KB
            unsigned long long keys[K];          // 16 KB sorted keys
            unsigned long long lcm[NC * NCHUNK]; // 20 KB class masks
            unsigned long long kept[NCHUNK];     // finisher: kept words
            unsigned kcpref[NCHUNK];             // finisher: kept prefix
            int total;                           // finisher: total kept
            int oflag;                           // finisher-block flag
        } c;
    } U;
    __shared__ unsigned wsum[16];

    int bid = blockIdx.x;
    int t = threadIdx.x;
    int ln = t & 63, wv = t >> 6;
    unsigned long long below = (ln == 0) ? 0ULL : (~0ULL >> (64 - ln));

    if (bid < B) {
        // ================= SELECT role =================
        int b = bid;
        constexpr int NITER = (N + 1023) / 1024;    // 25

        {   // zero histogram + cursors (24 KB)
            uint4 z = {0u, 0u, 0u, 0u};
            uint4* d1 = (uint4*)U.s.loff;
            for (int k = t; k < (NBUCKET + NBUCKET / 2) / 4; k += 1024) d1[k] = z;
        }
        for (int k = t; k < CAND_CAP; k += 1024) U.s.lk[k] = 0ULL;
        __syncthreads();

        // histogram pass: single global read, cache scores in registers
        float sreg[NITER];
        #pragma unroll
        for (int r = 0; r < NITER; ++r) {
            int i = t + r * 1024;
            float s = (i < N) ? scores[b * N + i] : -1.0f;
            sreg[r] = s;
            if (s > 0.0f) {
                int q = (int)(__fmul_rn(s, 4096.0f));
                if (q > NBUCKET - 1) q = NBUCKET - 1;
                atomicAdd(&U.s.loff[q], 1u);
            }
        }
        __syncthreads();

        // descending exclusive scan in place: loff[q] = count in buckets > q.
        // thread t owns buckets 4095-4t .. 4092-4t (uint4 index 1023-t).
        unsigned v[4];
        unsigned A4 = (unsigned)(NBUCKET / 4 - 1 - t);
        {
            uint4 u0 = ((uint4*)U.s.loff)[A4];
            v[0] = u0.w; v[1] = u0.z; v[2] = u0.y; v[3] = u0.x;
        }
        unsigned S = v[0] + v[1] + v[2] + v[3];
        unsigned pref = S;
        #pragma unroll
        for (int o = 1; o < 64; o <<= 1) { unsigned u = __shfl_up(pref, o, 64); if (ln >= o) pref += u; }
        if (ln == 63) wsum[wv] = pref;
        __syncthreads();
        unsigned wbase = 0;
        for (int w = 0; w < wv; ++w) wbase += wsum[w];
        unsigned running = wbase + pref - S;
        {
            unsigned o[4];
            #pragma unroll
            for (int k = 0; k < 4; ++k) { o[3 - k] = running; running += v[k]; }
            ((uint4*)U.s.loff)[A4] = make_uint4(o[0], o[1], o[2], o[3]);
        }
        __syncthreads();

        // placement (counting sort) from register-cached scores
        #pragma unroll
        for (int r = 0; r < NITER; ++r) {
            float s = sreg[r];
            if (s > 0.0f) {
                int i = t + r * 1024;
                int q = (int)(__fmul_rn(s, 4096.0f));
                if (q > NBUCKET - 1) q = NBUCKET - 1;
                unsigned start = U.s.loff[q];
                if (start < CAND_CAP) {
                    unsigned sh = (q & 1) * 16;
                    unsigned old = atomicAdd(&U.s.lcnt16[q >> 1], 1u << sh);
                    unsigned rank = (old >> sh) & 0xFFFFu;
                    unsigned pos = start + rank;
                    if (pos < CAND_CAP) {
                        unsigned long long key =
                            ((unsigned long long)__float_as_uint(s) << 32) | (unsigned)(~i);
                        U.s.lk[pos] = key;
                    }
                }
            }
        }
        __syncthreads();

        // per-bucket insertion sort (descending keys), disjoint ranges
        for (int q = t; q < NBUCKET; q += 1024) {
            unsigned start = U.s.loff[q];
            if (start < CAND_CAP) {
                unsigned c = (U.s.lcnt16[q >> 1] >> ((q & 1) * 16)) & 0xFFFFu;
                unsigned m = c;
                if (m > CAND_CAP - start) m = CAND_CAP - start;
                if (m >= 2) {
                    for (unsigned a = start + 1; a < start + m; ++a) {
                        unsigned long long kv = U.s.lk[a];
                        unsigned p2 = a;
                        while (p2 > start && U.s.lk[p2 - 1] < kv) { U.s.lk[p2] = U.s.lk[p2 - 1]; --p2; }
                        U.s.lk[p2] = kv;
                    }
                }
            }
        }
        __syncthreads();

        // export the top-K sorted keys (coalesced, 16 KB) and release
        for (int r = t; r < K; r += 1024)
            gkeys[(size_t)b * K + r] = U.s.lk[r];
        __syncthreads();
        if (t == 0) {
            __threadfence();
            atomicExch(&ready[b * CTR_STRIDE], 1u);
        }
        return;
    }

    // ================= CLASS-NMS role =================
    int gid = bid - B;          // 0..39
    int b = gid / 5;
    int grp = gid % 5;
    int c = grp * 16 + wv;      // this wave's class, 0..79

    // acquire: spin on ready[b], invalidate caches, block-wide barrier
    if (t == 0) {
        U.c.oflag = 0;
        while (atomicOr(&ready[b * CTR_STRIDE], 0u) == 0u)
            __builtin_amdgcn_s_sleep(8);
        __threadfence();
    }
    __syncthreads();

    // load sorted keys -> LDS; zero class masks
    for (int r = t; r < K; r += 1024) U.c.keys[r] = gkeys[(size_t)b * K + r];
    for (int k = t; k < NC * NCHUNK; k += 1024) U.c.lcm[k] = 0ULL;
    __syncthreads();

    // parallel class-mask build (1024 threads x 2 ranks)
    for (int r = t; r < K; r += 1024) {
        unsigned long long key = U.c.keys[r];
        if (key != 0ULL) {
            int idx = (int)(~(unsigned)key);
            int cc = cls_id[b * N + idx];
            atomicOr(&U.c.lcm[cc * NCHUNK + (r >> 6)], 1ULL << (r & 63));
        }
    }
    __syncthreads();

    // register compaction from LDS masks: lane ln -> ln-th member of class c
    int n = 0, r = -1, ch_i = -1, myk = -1;
    unsigned long long mych = 0ULL;
    for (int ch = 0; ch < NCHUNK; ++ch) {
        unsigned long long m = U.c.lcm[c * NCHUNK + ch];   // LDS, wave-uniform
        int cnt = __popcll(m);
        if (myk < 0 && ln < n + cnt) { mych = m; myk = ln - n; ch_i = ch; }
        n += cnt;
    }
    if (myk >= 0) {
        unsigned long long mm = mych;
        for (int z = 0; z < myk; ++z) mm &= mm - 1;
        r = ch_i * 64 + (int)__builtin_ctzll(mm);
    }

    float shf = __fmul_rn((float)c, 4096.0f);   // class shift (uniform)

    if (n > 0 && n <= 64) {
        // fast path: member ln computes its shifted box in-lane from boxes4
        float x1 = 0.f, y1 = 0.f, x2 = 0.f, y2 = 0.f, ar = 0.f;
        if (ln < n) {
            unsigned long long key = U.c.keys[r];
            int idx = (int)(~(unsigned)key);
            float4 bb = boxes4[(size_t)b * N + idx];
            x1 = __fadd_rn(bb.x, shf); y1 = __fadd_rn(bb.y, shf);
            x2 = __fadd_rn(bb.z, shf); y2 = __fadd_rn(bb.w, shf);
            ar = __fmul_rn(__fsub_rn(x2, x1), __fsub_rn(y2, y1));
        }
        unsigned long long keepw = (n == 64) ? ~0ULL : ((1ULL << n) - 1ULL);
        for (int i = 0; i < n; ++i) {
            if (!((keepw >> i) & 1ULL)) continue;   // uniform
            float bx1 = __shfl(x1, i, 64), by1 = __shfl(y1, i, 64);
            float bx2 = __shfl(x2, i, 64), by2 = __shfl(y2, i, 64);
            float ba  = __shfl(ar, i, 64);
            bool cond = false;
            if (ln > i && ln < n) {
                float lx = fmaxf(bx1, x1), ly = fmaxf(by1, y1);
                float rx = fminf(bx2, x2), ry = fminf(by2, y2);
                float w = fmaxf(__fsub_rn(rx, lx), 0.0f);
                float h = fmaxf(__fsub_rn(ry, ly), 0.0f);
                float inter = __fmul_rn(w, h);
                float denom = __fadd_rn(__fsub_rn(__fadd_rn(ba, ar), inter), 1e-9f);
                cond = __fdiv_rn(inter, denom) > 0.6f;   // exact ref order
            }
            keepw &= ~__ballot(cond);
        }
        if (ln < n && ((keepw >> ln) & 1ULL))
            atomicOr(&keepbits[b * NCHUNK + (r >> 6)], 1ULL << (r & 63));
    } else if (n > 64) {
        // general path (n > 64): wave-local register-distributed keep bits.
        // Correctness-only; unreachable for this data distribution.
        unsigned long long membw = (ln < NCHUNK) ? U.c.lcm[c * NCHUNK + ln] : 0ULL;
        unsigned long long keepw2 = membw;
        for (int i = 0; i < K; ++i) {
            int ch = i >> 6;
            unsigned long long mw = __shfl(membw, ch, 64);
            unsigned long long kw = __shfl(keepw2, ch, 64);
            unsigned long long bi = 1ULL << (i & 63);
            if (!(mw & kw & bi)) continue;   // uniform (shfl results uniform)
            unsigned long long keyi = U.c.keys[i];             // uniform
            int idxi = (int)(~(unsigned)keyi);
            float4 bi4 = boxes4[(size_t)b * N + idxi];
            float bx1 = __fadd_rn(bi4.x, shf), by1 = __fadd_rn(bi4.y, shf);
            float bx2 = __fadd_rn(bi4.z, shf), by2 = __fadd_rn(bi4.w, shf);
            float ba = __fmul_rn(__fsub_rn(bx2, bx1), __fsub_rn(by2, by1));
            for (int c2 = ch; c2 < NCHUNK; ++c2) {
                int j = c2 * 64 + ln;
                unsigned long long mw2 = __shfl(membw, c2, 64);
                bool cond = false;
                if (j > i && ((mw2 >> ln) & 1ULL)) {
                    unsigned long long keyj = U.c.keys[j];
                    int idxj = (int)(~(unsigned)keyj);
                    float4 bj4 = boxes4[(size_t)b * N + idxj];
                    float x1 = __fadd_rn(bj4.x, shf), y1 = __fadd_rn(bj4.y, shf);
                    float x2 = __fadd_rn(bj4.z, shf), y2 = __fadd_rn(bj4.w, shf);
                    float arj = __fmul_rn(__fsub_rn(x2, x1), __fsub_rn(y2, y1));
                    float lx = fmaxf(bx1, x1), ly = fmaxf(by1, y1);
                    float rx = fminf(bx2, x2), ry = fminf(by2, y2);
                    float w = fmaxf(__fsub_rn(rx, lx), 0.0f);
                    float h = fmaxf(__fsub_rn(ry, ly), 0.0f);
                    float inter = __fmul_rn(w, h);
                    float denom = __fadd_rn(__fsub_rn(__fadd_rn(ba, arj), inter), 1e-9f);
                    cond = __fdiv_rn(inter, denom) > 0.6f;
                }
                unsigned long long sup = __ballot(cond);
                if (ln == c2) keepw2 &= ~sup;
            }
        }
        if (ln < NCHUNK && (keepw2 & membw))
            atomicOr(&keepbits[b * NCHUNK + ln], keepw2 & membw);
    }

    // ---- last-finisher detection + BLOCK-parallel output phase ----
    __threadfence();
    unsigned old = 0;
    if (ln == 0) old = atomicAdd(&done_ctr[b * CTR_STRIDE], 1u);
    old = (unsigned)__shfl((int)old, 0, 64);
    if (old == NC - 1) {
        // finisher wave: coherent kept read + per-chunk prefix into LDS
        __threadfence();
        unsigned long long kwv = 0ULL;
        if (ln < NCHUNK) kwv = atomicOr(&keepbits[b * NCHUNK + ln], 0ULL);
        unsigned pc = (unsigned)__popcll(kwv);
        unsigned incl = pc;
        #pragma unroll
        for (int o = 1; o < 32; o <<= 1) { unsigned u = __shfl_up(incl, o, 64); if (ln >= o) incl += u; }
        if (ln < NCHUNK) {
            U.c.kept[ln] = kwv;
            U.c.kcpref[ln] = incl - pc;      // exclusive kept prefix
        }
        if (ln == 31) U.c.total = (int)incl; // total kept
        if (ln == 0)  U.c.oflag = 1;
    }
    __syncthreads();

    if (U.c.oflag) {
        int total = U.c.total;
        float* dets  = out + (size_t)b * MAXDET * 6;
        float* flags = out + (size_t)B * MAXDET * 6 + (size_t)b * MAXDET;
        #pragma unroll
        for (int h = 0; h < 2; ++h) {
            int ch = wv * 2 + h;
            int i = ch * 64 + ln;
            unsigned long long m = U.c.kept[ch];
            bool k = ((m >> ln) & 1ULL) != 0ULL;
            int kp = (int)U.c.kcpref[ch];
            int np = ch * 64 - kp;           // exclusive non-kept prefix
            int slot = k ? (kp + (int)__popcll(m & below))
                         : (total + np + (int)__popcll((~m) & below));
            if (slot < MAXDET) {
                unsigned long long key = U.c.keys[i];
                float s, ox1, oy1, ox2, oy2; int oc;
                if (key == 0ULL) {
                    s = -1.0f; ox1 = oy1 = ox2 = oy2 = 0.0f; oc = 0;
                } else {
                    s = __uint_as_float((unsigned)(key >> 32));
                    int idx = (int)(~(unsigned)key);
                    float4 bb = boxes4[(size_t)b * N + idx];
                    ox1 = bb.x; oy1 = bb.y; ox2 = bb.z; oy2 = bb.w;
                    oc = cls_id[b * N + idx];
                }
                dets[slot * 6 + 0] = ox1;
                dets[slot * 6 + 1] = oy1;
                dets[slot * 6 + 2] = ox2;
                dets[slot * 6 + 3] = oy2;
                dets[slot * 6 + 4] = s;
                dets[slot * 6 + 5] = (float)oc;
                flags[slot] = k ? 1.0f : 0.0f;
            }
        }
    }
}

// ---------------------------------------------------------------------------
extern "C" void kernel_launch(void* const* d_in, const int* in_sizes, int n_in,
                              void* d_out, int out_size, void* d_ws, size_t ws_size,
                              hipStream_t stream) {
    const float* x = (const float*)d_in[0];
    float* out = (float*)d_out;

    char* ws = (char*)d_ws;
    size_t off = 0;
    auto alloc = [&](size_t bytes) -> void* {
        void* p = ws + off;
        off += bytes;
        off = (off + 255) & ~(size_t)255;
        return p;
    };

    float*    scores = (float*)    alloc((size_t)B * N * 4);
    int*      cls_id = (int*)      alloc((size_t)B * N * 4);
    float4*   boxes4 = (float4*)   alloc((size_t)B * N * 16);
    unsigned long long* gkeys    = (unsigned long long*) alloc((size_t)B * K * 8);
    unsigned long long* keepbits = (unsigned long long*) alloc((size_t)B * NCHUNK * 8);
    unsigned* ready    = (unsigned*) alloc((size_t)B * CTR_STRIDE * 4);
    unsigned* done_ctr = (unsigned*) alloc((size_t)B * CTR_STRIDE * 4);
    (void)ws_size; // needs ~2.7 MB

    nms_score_kernel<<<dim3((N + STILE - 1) / STILE, B), 256, 0, stream>>>(
        x, scores, cls_id, boxes4, ready, done_ctr, keepbits);
    nms_tail_kernel<<<B + 5 * B, 1024, 0, stream>>>(
        scores, boxes4, cls_id, gkeys, keepbits, ready, done_ctr, out);
}

// Round 10
// 136.266 us; speedup vs baseline: 1.2522x; 1.0242x over previous
//
#include <hip/hip_runtime.h>

#define B 8
#define N 25200
#define ROW 85
#define NC 80
#define K 2048
#define MAXDET 300
#define NBUCKET 4096
#define CAND_CAP 4096
#define NCHUNK 32   /* K/64 */
#define STILE 64    /* score tile rows */
#define CTR_STRIDE 64   /* u32 stride per batch counter: 256B, no false sharing */

// ---------------------------------------------------------------------------
// Kernel 1: score/cls per box + xyxy boxes4 (bit-identical box math).
// Block (0,b) also zeroes done counter and keepbits for kernel 2.
// ---------------------------------------------------------------------------
__global__ void __launch_bounds__(256)
nms_score_kernel(const float* __restrict__ x,
                 float* __restrict__ scores,
                 int* __restrict__ cls_id,
                 float4* __restrict__ boxes4,
                 unsigned* __restrict__ done_ctr,
                 unsigned long long* __restrict__ keepbits) {
    int b = blockIdx.y;
    int i0 = blockIdx.x * STILE;
    if (blockIdx.x == 0) {
        if (threadIdx.x == 0) done_ctr[b * CTR_STRIDE] = 0u;
        if (threadIdx.x < NCHUNK) keepbits[b * NCHUNK + threadIdx.x] = 0ULL;
    }
    int rows = N - i0; if (rows > STILE) rows = STILE;
    __shared__ float lx[STILE * ROW];   // 21760 B
    {
        const float4* s4 = (const float4*)(x + ((size_t)b * N + i0) * ROW);
        float4* d4 = (float4*)lx;
        int nv = rows * ROW / 4;        // 1360 or 1020 (both exact)
        for (int k = threadIdx.x; k < nv; k += 256) d4[k] = s4[k];
    }
    __syncthreads();
    int g = threadIdx.x >> 2;          // box in tile
    int q = threadIdx.x & 3;
    if (g >= rows) return;             // uniform across the 4-lane group
    const float* p = lx + g * ROW;
    float obj = p[4];
    float best = -1e30f;
    int bc = 127;
    if (obj > 0.3f) {
        #pragma unroll
        for (int k = 0; k < 20; ++k) {
            int c = q + 4 * k;
            float v = __fmul_rn(p[5 + c], obj);   // exact, no FMA
            if (v > best) { best = v; bc = c; }   // strict >: in-lane first-max
        }
    }
    #pragma unroll
    for (int m = 1; m < 4; m <<= 1) {   // combine: higher v, tie -> smaller class
        float ov = __shfl_xor(best, m, 64);
        int   oc = __shfl_xor(bc, m, 64);
        if (ov > best || (ov == best && oc < bc)) { best = ov; bc = oc; }
    }
    if (q == 0) {
        int i = i0 + g;
        float score = (obj > 0.3f && best > 0.3f) ? best : -1.0f;
        scores[b * N + i] = score;
        cls_id[b * N + i] = (bc == 127) ? 0 : bc;
        float cx = p[0], cy = p[1], w = p[2], h = p[3];
        float hx = __fmul_rn(w, 0.5f);
        float hy = __fmul_rn(h, 0.5f);
        boxes4[b * N + i] = make_float4(__fsub_rn(cx, hx), __fsub_rn(cy, hy),
                                        __fadd_rn(cx, hx), __fadd_rn(cy, hy));
    }
}

// ---------------------------------------------------------------------------
// Kernel 2 (tail): 40 blocks x 1024 threads, ONE role. Block bid handles
// batch bid/5, classes (bid%5)*16 + wv. Each block REPLICATES the full
// top-K select for its batch in LDS (duplication across 5 blocks is free —
// parallel CUs — and removes the producer->consumer fence/spin/reload chain
// that R9 measured as the dominant tail cost):
//   zero -> histogram -> scan -> placement -> per-bucket key sort
//   -> LDS->LDS key copy -> class-mask build -> per-wave greedy NMS
//   -> keepbits atomicOr -> done_ctr last-finisher emits dets/flags.
// Key construction, sort, NMS fp sequence, and output logic byte-identical
// to R9 (absmax 0.0 structurally).
// ---------------------------------------------------------------------------
__global__ void __launch_bounds__(1024, 1)
nms_tail_kernel(const float* __restrict__ scores,
                const float4* __restrict__ boxes4,
                const int* __restrict__ cls_id,
                unsigned long long* __restrict__ keepbits,
                unsigned* __restrict__ done_ctr,
                float* __restrict__ out) {
    __shared__ union {
        struct {   // SELECT phase: 56 KB
            unsigned loff[NBUCKET];              // 16 KB hist -> start ranks
            unsigned lcnt16[NBUCKET / 2];        // 8 KB packed u16 cursors
            unsigned long long lk[CAND_CAP];     // 32 KB sort keys @ byte 24K
        } s;
        struct {   // NMS phase: ~37 KB
            unsigned long long keys[K];          // 16 KB sorted keys @ byte 0
            unsigned long long lcm[NC * NCHUNK]; // 20 KB class masks @ 16K
            unsigned long long kept[NCHUNK];     // finisher: kept words
            unsigned kcpref[NCHUNK];             // finisher: kept prefix
            int total;                           // finisher: total kept
            int oflag;                           // finisher-block flag
        } c;
    } U;
    __shared__ unsigned wsum[16];

    int bid = blockIdx.x;
    int t = threadIdx.x;
    int ln = t & 63, wv = t >> 6;
    unsigned long long below = (ln == 0) ? 0ULL : (~0ULL >> (64 - ln));

    int b = bid / 5;
    int grp = bid % 5;
    int c = grp * 16 + wv;      // this wave's class, 0..79
    constexpr int NITER = (N + 1023) / 1024;    // 25

    // ================= SELECT phase (replicated per block) =================
    {   // zero histogram + cursors (24 KB)
        uint4 z = {0u, 0u, 0u, 0u};
        uint4* d1 = (uint4*)U.s.loff;
        for (int k = t; k < (NBUCKET + NBUCKET / 2) / 4; k += 1024) d1[k] = z;
    }
    for (int k = t; k < CAND_CAP; k += 1024) U.s.lk[k] = 0ULL;
    __syncthreads();

    // histogram pass: single global read, cache scores in registers
    float sreg[NITER];
    #pragma unroll
    for (int r = 0; r < NITER; ++r) {
        int i = t + r * 1024;
        float s = (i < N) ? scores[b * N + i] : -1.0f;
        sreg[r] = s;
        if (s > 0.0f) {
            int q = (int)(__fmul_rn(s, 4096.0f));
            if (q > NBUCKET - 1) q = NBUCKET - 1;
            atomicAdd(&U.s.loff[q], 1u);
        }
    }
    __syncthreads();

    // descending exclusive scan in place: loff[q] = count in buckets > q.
    // thread t owns buckets 4095-4t .. 4092-4t (uint4 index 1023-t).
    {
        unsigned v[4];
        unsigned A4 = (unsigned)(NBUCKET / 4 - 1 - t);
        {
            uint4 u0 = ((uint4*)U.s.loff)[A4];
            v[0] = u0.w; v[1] = u0.z; v[2] = u0.y; v[3] = u0.x;
        }
        unsigned S = v[0] + v[1] + v[2] + v[3];
        unsigned pref = S;
        #pragma unroll
        for (int o = 1; o < 64; o <<= 1) { unsigned u = __shfl_up(pref, o, 64); if (ln >= o) pref += u; }
        if (ln == 63) wsum[wv] = pref;
        __syncthreads();
        unsigned wbase = 0;
        for (int w = 0; w < wv; ++w) wbase += wsum[w];
        unsigned running = wbase + pref - S;
        unsigned o[4];
        #pragma unroll
        for (int k = 0; k < 4; ++k) { o[3 - k] = running; running += v[k]; }
        ((uint4*)U.s.loff)[A4] = make_uint4(o[0], o[1], o[2], o[3]);
    }
    __syncthreads();

    // placement (counting sort) from register-cached scores
    #pragma unroll
    for (int r = 0; r < NITER; ++r) {
        float s = sreg[r];
        if (s > 0.0f) {
            int i = t + r * 1024;
            int q = (int)(__fmul_rn(s, 4096.0f));
            if (q > NBUCKET - 1) q = NBUCKET - 1;
            unsigned start = U.s.loff[q];
            if (start < CAND_CAP) {
                unsigned sh = (q & 1) * 16;
                unsigned old = atomicAdd(&U.s.lcnt16[q >> 1], 1u << sh);
                unsigned rank = (old >> sh) & 0xFFFFu;
                unsigned pos = start + rank;
                if (pos < CAND_CAP) {
                    unsigned long long key =
                        ((unsigned long long)__float_as_uint(s) << 32) | (unsigned)(~i);
                    U.s.lk[pos] = key;
                }
            }
        }
    }
    __syncthreads();

    // per-bucket insertion sort (descending keys), disjoint ranges
    for (int q = t; q < NBUCKET; q += 1024) {
        unsigned start = U.s.loff[q];
        if (start < CAND_CAP) {
            unsigned cc = (U.s.lcnt16[q >> 1] >> ((q & 1) * 16)) & 0xFFFFu;
            unsigned m = cc;
            if (m > CAND_CAP - start) m = CAND_CAP - start;
            if (m >= 2) {
                for (unsigned a = start + 1; a < start + m; ++a) {
                    unsigned long long kv = U.s.lk[a];
                    unsigned p2 = a;
                    while (p2 > start && U.s.lk[p2 - 1] < kv) { U.s.lk[p2] = U.s.lk[p2 - 1]; --p2; }
                    U.s.lk[p2] = kv;
                }
            }
        }
    }
    __syncthreads();

    // ================= transition: keys <- lk (disjoint LDS regions) =======
    // keys @ bytes [0,16K) ; lk @ bytes [24K,56K) -> safe concurrent copy.
    for (int r = t; r < K; r += 1024) U.c.keys[r] = U.s.lk[r];
    __syncthreads();
    // lcm @ [16K,36.8K) overlaps dead lcnt16/lk only after the copy barrier.
    for (int k = t; k < NC * NCHUNK; k += 1024) U.c.lcm[k] = 0ULL;
    if (t == 0) U.c.oflag = 0;
    __syncthreads();

    // parallel class-mask build (1024 threads x 2 ranks)
    for (int r = t; r < K; r += 1024) {
        unsigned long long key = U.c.keys[r];
        if (key != 0ULL) {
            int idx = (int)(~(unsigned)key);
            int cc = cls_id[b * N + idx];
            atomicOr(&U.c.lcm[cc * NCHUNK + (r >> 6)], 1ULL << (r & 63));
        }
    }
    __syncthreads();

    // ================= per-wave class NMS =================
    // register compaction from LDS masks: lane ln -> ln-th member of class c
    int n = 0, r = -1, ch_i = -1, myk = -1;
    unsigned long long mych = 0ULL;
    for (int ch = 0; ch < NCHUNK; ++ch) {
        unsigned long long m = U.c.lcm[c * NCHUNK + ch];   // LDS, wave-uniform
        int cnt = __popcll(m);
        if (myk < 0 && ln < n + cnt) { mych = m; myk = ln - n; ch_i = ch; }
        n += cnt;
    }
    if (myk >= 0) {
        unsigned long long mm = mych;
        for (int z = 0; z < myk; ++z) mm &= mm - 1;
        r = ch_i * 64 + (int)__builtin_ctzll(mm);
    }

    float shf = __fmul_rn((float)c, 4096.0f);   // class shift (uniform)

    if (n > 0 && n <= 64) {
        // fast path: member ln computes its shifted box in-lane from boxes4
        float x1 = 0.f, y1 = 0.f, x2 = 0.f, y2 = 0.f, ar = 0.f;
        if (ln < n) {
            unsigned long long key = U.c.keys[r];
            int idx = (int)(~(unsigned)key);
            float4 bb = boxes4[(size_t)b * N + idx];
            x1 = __fadd_rn(bb.x, shf); y1 = __fadd_rn(bb.y, shf);
            x2 = __fadd_rn(bb.z, shf); y2 = __fadd_rn(bb.w, shf);
            ar = __fmul_rn(__fsub_rn(x2, x1), __fsub_rn(y2, y1));
        }
        unsigned long long keepw = (n == 64) ? ~0ULL : ((1ULL << n) - 1ULL);
        for (int i = 0; i < n; ++i) {
            if (!((keepw >> i) & 1ULL)) continue;   // uniform
            float bx1 = __shfl(x1, i, 64), by1 = __shfl(y1, i, 64);
            float bx2 = __shfl(x2, i, 64), by2 = __shfl(y2, i, 64);
            float ba  = __shfl(ar, i, 64);
            bool cond = false;
            if (ln > i && ln < n) {
                float lx = fmaxf(bx1, x1), ly = fmaxf(by1, y1);
                float rx = fminf(bx2, x2), ry = fminf(by2, y2);
                float w = fmaxf(__fsub_rn(rx, lx), 0.0f);
                float h = fmaxf(__fsub_rn(ry, ly), 0.0f);
                float inter = __fmul_rn(w, h);
                float denom = __fadd_rn(__fsub_rn(__fadd_rn(ba, ar), inter), 1e-9f);
                cond = __fdiv_rn(inter, denom) > 0.6f;   // exact ref order
            }
            keepw &= ~__ballot(cond);
        }
        if (ln < n && ((keepw >> ln) & 1ULL))
            atomicOr(&keepbits[b * NCHUNK + (r >> 6)], 1ULL << (r & 63));
    } else if (n > 64) {
        // general path (n > 64): wave-local register-distributed keep bits.
        // Correctness-only; unreachable for this data distribution.
        unsigned long long membw = (ln < NCHUNK) ? U.c.lcm[c * NCHUNK + ln] : 0ULL;
        unsigned long long keepw2 = membw;
        for (int i = 0; i < K; ++i) {
            int ch = i >> 6;
            unsigned long long mw = __shfl(membw, ch, 64);
            unsigned long long kw = __shfl(keepw2, ch, 64);
            unsigned long long bi = 1ULL << (i & 63);
            if (!(mw & kw & bi)) continue;   // uniform (shfl results uniform)
            unsigned long long keyi = U.c.keys[i];             // uniform
            int idxi = (int)(~(unsigned)keyi);
            float4 bi4 = boxes4[(size_t)b * N + idxi];
            float bx1 = __fadd_rn(bi4.x, shf), by1 = __fadd_rn(bi4.y, shf);
            float bx2 = __fadd_rn(bi4.z, shf), by2 = __fadd_rn(bi4.w, shf);
            float ba = __fmul_rn(__fsub_rn(bx2, bx1), __fsub_rn(by2, by1));
            for (int c2 = ch; c2 < NCHUNK; ++c2) {
                int j = c2 * 64 + ln;
                unsigned long long mw2 = __shfl(membw, c2, 64);
                bool cond = false;
                if (j > i && ((mw2 >> ln) & 1ULL)) {
                    unsigned long long keyj = U.c.keys[j];
                    int idxj = (int)(~(unsigned)keyj);
                    float4 bj4 = boxes4[(size_t)b * N + idxj];
                    float x1 = __fadd_rn(bj4.x, shf), y1 = __fadd_rn(bj4.y, shf);
                    float x2 = __fadd_rn(bj4.z, shf), y2 = __fadd_rn(bj4.w, shf);
                    float arj = __fmul_rn(__fsub_rn(x2, x1), __fsub_rn(y2, y1));
                    float lx = fmaxf(bx1, x1), ly = fmaxf(by1, y1);
                    float rx = fminf(bx2, x2), ry = fminf(by2, y2);
                    float w = fmaxf(__fsub_rn(rx, lx), 0.0f);
                    float h = fmaxf(__fsub_rn(ry, ly), 0.0f);
                    float inter = __fmul_rn(w, h);
                    float denom = __fadd_rn(__fsub_rn(__fadd_rn(ba, arj), inter), 1e-9f);
                    cond = __fdiv_rn(inter, denom) > 0.6f;
                }
                unsigned long long sup = __ballot(cond);
                if (ln == c2) keepw2 &= ~sup;
            }
        }
        if (ln < NCHUNK && (keepw2 & membw))
            atomicOr(&keepbits[b * NCHUNK + ln], keepw2 & membw);
    }

    // ---- last-finisher detection + BLOCK-parallel output phase ----
    __threadfence();
    unsigned old = 0;
    if (ln == 0) old = atomicAdd(&done_ctr[b * CTR_STRIDE], 1u);
    old = (unsigned)__shfl((int)old, 0, 64);
    if (old == NC - 1) {
        // finisher wave: coherent kept read + per-chunk prefix into LDS
        __threadfence();
        unsigned long long kwv = 0ULL;
        if (ln < NCHUNK) kwv = atomicOr(&keepbits[b * NCHUNK + ln], 0ULL);
        unsigned pc = (unsigned)__popcll(kwv);
        unsigned incl = pc;
        #pragma unroll
        for (int o = 1; o < 32; o <<= 1) { unsigned u = __shfl_up(incl, o, 64); if (ln >= o) incl += u; }
        if (ln < NCHUNK) {
            U.c.kept[ln] = kwv;
            U.c.kcpref[ln] = incl - pc;      // exclusive kept prefix
        }
        if (ln == 31) U.c.total = (int)incl; // total kept
        if (ln == 0)  U.c.oflag = 1;
    }
    __syncthreads();

    if (U.c.oflag) {
        int total = U.c.total;
        float* dets  = out + (size_t)b * MAXDET * 6;
        float* flags = out + (size_t)B * MAXDET * 6 + (size_t)b * MAXDET;
        #pragma unroll
        for (int h = 0; h < 2; ++h) {
            int ch = wv * 2 + h;
            int i = ch * 64 + ln;
            unsigned long long m = U.c.kept[ch];
            bool k = ((m >> ln) & 1ULL) != 0ULL;
            int kp = (int)U.c.kcpref[ch];
            int np = ch * 64 - kp;           // exclusive non-kept prefix
            int slot = k ? (kp + (int)__popcll(m & below))
                         : (total + np + (int)__popcll((~m) & below));
            if (slot < MAXDET) {
                unsigned long long key = U.c.keys[i];
                float s, ox1, oy1, ox2, oy2; int oc;
                if (key == 0ULL) {
                    s = -1.0f; ox1 = oy1 = ox2 = oy2 = 0.0f; oc = 0;
                } else {
                    s = __uint_as_float((unsigned)(key >> 32));
                    int idx = (int)(~(unsigned)key);
                    float4 bb = boxes4[(size_t)b * N + idx];
                    ox1 = bb.x; oy1 = bb.y; ox2 = bb.z; oy2 = bb.w;
                    oc = cls_id[b * N + idx];
                }
                dets[slot * 6 + 0] = ox1;
                dets[slot * 6 + 1] = oy1;
                dets[slot * 6 + 2] = ox2;
                dets[slot * 6 + 3] = oy2;
                dets[slot * 6 + 4] = s;
                dets[slot * 6 + 5] = (float)oc;
                flags[slot] = k ? 1.0f : 0.0f;
            }
        }
    }
}

// ---------------------------------------------------------------------------
extern "C" void kernel_launch(void* const* d_in, const int* in_sizes, int n_in,
                              void* d_out, int out_size, void* d_ws, size_t ws_size,
                              hipStream_t stream) {
    const float* x = (const float*)d_in[0];
    float* out = (float*)d_out;

    char* ws = (char*)d_ws;
    size_t off = 0;
    auto alloc = [&](size_t bytes) -> void* {
        void* p = ws + off;
        off += bytes;
        off = (off + 255) & ~(size_t)255;
        return p;
    };

    float*    scores = (float*)    alloc((size_t)B * N * 4);
    int*      cls_id = (int*)      alloc((size_t)B * N * 4);
    float4*   boxes4 = (float4*)   alloc((size_t)B * N * 16);
    unsigned long long* keepbits = (unsigned long long*) alloc((size_t)B * NCHUNK * 8);
    unsigned* done_ctr = (unsigned*) alloc((size_t)B * CTR_STRIDE * 4);
    (void)ws_size; // needs ~2.6 MB

    nms_score_kernel<<<dim3((N + STILE - 1) / STILE, B), 256, 0, stream>>>(
        x, scores, cls_id, boxes4, done_ctr, keepbits);
    nms_tail_kernel<<<5 * B, 1024, 0, stream>>>(
        scores, boxes4, cls_id, keepbits, done_ctr, out);
}